// Round 1
// baseline (215.153 us; speedup 1.0000x reference)
//
#include <hip/hip_runtime.h>

// Problem constants (from reference): x[B,D,H,W], codewords[K,D], scale[K]
#define BB 16
#define DD 512
#define NN 4096   // H*W
#define KK 32
#define TILE_N 256
#define BLK 256
#define APAD 36   // padded row of a_sm in floats (144B, 16B-aligned)

__global__ __launch_bounds__(BLK, 1)
void encoding_fused(const float* __restrict__ x,
                    const float* __restrict__ cw,
                    const float* __restrict__ scale,
                    float* __restrict__ out) {
    __shared__ float c_t[DD][KK];          // 64 KB, c_t[d][k] = cw[k][d]
    __shared__ float a_sm[TILE_N][APAD];   // 36 KB, xc then a
    __shared__ float x2_sm[TILE_N];
    __shared__ float c2_sm[KK];
    __shared__ float s2_sm[KK];
    __shared__ float asum_part[8][KK];
    __shared__ float asum_sm[KK];

    const int t = threadIdx.x;
    const int b = blockIdx.x >> 4;       // 16 tiles per batch
    const int tile = blockIdx.x & 15;
    const int n0 = tile * TILE_N;
    const float* xb = x + (size_t)b * DD * NN;

    // ---- load codewords transposed into LDS ----
    for (int i = t; i < KK * DD; i += BLK) {
        int k = i >> 9;      // /512
        int d = i & 511;
        c_t[d][k] = cw[i];
    }
    __syncthreads();
    if (t < KK) {
        float s = scale[t];
        s2_sm[t] = s * s;
        float c2 = 0.f;
        for (int d = 0; d < DD; ++d) { float v = c_t[d][t]; c2 += v * v; }
        c2_sm[t] = c2;
    }
    __syncthreads();

    // ---- Phase A: xc[n,k] and x2[n] for the 256-n tile ----
    // thread t: n-pair m = t&127 (n = n0+2m, n0+2m+1), d-half h = t>>7
    const int m = t & 127;
    const int h = t >> 7;
    const int na = 2 * m;
    float xc0[KK], xc1[KK];
#pragma unroll
    for (int k = 0; k < KK; ++k) { xc0[k] = 0.f; xc1[k] = 0.f; }
    float x20 = 0.f, x21 = 0.f;
    const float* xp = xb + (size_t)(h * 256) * NN + n0 + na;
    for (int dd = 0; dd < 256; ++dd) {
        float2 xv = *reinterpret_cast<const float2*>(xp);
        xp += NN;
        const float4* cr = reinterpret_cast<const float4*>(&c_t[h * 256 + dd][0]);
#pragma unroll
        for (int kq = 0; kq < 8; ++kq) {
            float4 c4 = cr[kq];
            xc0[kq * 4 + 0] += xv.x * c4.x;
            xc0[kq * 4 + 1] += xv.x * c4.y;
            xc0[kq * 4 + 2] += xv.x * c4.z;
            xc0[kq * 4 + 3] += xv.x * c4.w;
            xc1[kq * 4 + 0] += xv.y * c4.x;
            xc1[kq * 4 + 1] += xv.y * c4.y;
            xc1[kq * 4 + 2] += xv.y * c4.z;
            xc1[kq * 4 + 3] += xv.y * c4.w;
        }
        x20 += xv.x * xv.x;
        x21 += xv.y * xv.y;
    }
    // combine the two d-halves through LDS
    if (h == 0) {
#pragma unroll
        for (int k = 0; k < KK; ++k) { a_sm[na][k] = xc0[k]; a_sm[na + 1][k] = xc1[k]; }
        x2_sm[na] = x20; x2_sm[na + 1] = x21;
    }
    __syncthreads();
    if (h == 1) {
#pragma unroll
        for (int k = 0; k < KK; ++k) { a_sm[na][k] += xc0[k]; a_sm[na + 1][k] += xc1[k]; }
        x2_sm[na] += x20; x2_sm[na + 1] += x21;
    }
    __syncthreads();

    // ---- softmax over k, row per thread ----
    {
        float x2v = x2_sm[t];
        float sl[KK];
        float mx = -1e30f;
#pragma unroll
        for (int k = 0; k < KK; ++k) {
            float v = s2_sm[k] * (x2v - 2.f * a_sm[t][k] + c2_sm[k]);
            sl[k] = v;
            mx = fmaxf(mx, v);
        }
        float sum = 0.f;
#pragma unroll
        for (int k = 0; k < KK; ++k) { float p = __expf(sl[k] - mx); sl[k] = p; sum += p; }
        float inv = 1.f / sum;
#pragma unroll
        for (int k = 0; k < KK; ++k) a_sm[t][k] = sl[k] * inv;
    }
    __syncthreads();

    // ---- asum[k] = sum over tile rows of a ----
    {
        int k = t & 31, chunk = t >> 5;   // 8 chunks x 32 rows
        float s = 0.f;
        for (int r = chunk * 32; r < chunk * 32 + 32; ++r) s += a_sm[r][k];
        asum_part[chunk][k] = s;
    }
    __syncthreads();
    if (t < KK) {
        float s = 0.f;
#pragma unroll
        for (int c = 0; c < 8; ++c) s += asum_part[c][t];
        asum_sm[t] = s;
    }
    __syncthreads();

    // ---- Phase B: e[k,d] partial = sum_n a[n,k] * x[d,n] ----
    // thread t owns d0 = t, d1 = t+256; all 32 k
    float acc0[KK], acc1[KK];
#pragma unroll
    for (int k = 0; k < KK; ++k) { acc0[k] = 0.f; acc1[k] = 0.f; }
    const int d0 = t, d1 = t + 256;
    const float* xr0 = xb + (size_t)d0 * NN + n0;
    const float* xr1 = xb + (size_t)d1 * NN + n0;
    for (int g = 0; g < 64; ++g) {
        float4 xv0 = *reinterpret_cast<const float4*>(xr0 + 4 * g);
        float4 xv1 = *reinterpret_cast<const float4*>(xr1 + 4 * g);
        const float xs0[4] = {xv0.x, xv0.y, xv0.z, xv0.w};
        const float xs1[4] = {xv1.x, xv1.y, xv1.z, xv1.w};
#pragma unroll
        for (int j = 0; j < 4; ++j) {
            const float4* ar = reinterpret_cast<const float4*>(&a_sm[4 * g + j][0]);
            float a0 = xs0[j], a1 = xs1[j];
#pragma unroll
            for (int kq = 0; kq < 8; ++kq) {
                float4 a4 = ar[kq];
                acc0[kq * 4 + 0] += a0 * a4.x;
                acc0[kq * 4 + 1] += a0 * a4.y;
                acc0[kq * 4 + 2] += a0 * a4.z;
                acc0[kq * 4 + 3] += a0 * a4.w;
                acc1[kq * 4 + 0] += a1 * a4.x;
                acc1[kq * 4 + 1] += a1 * a4.y;
                acc1[kq * 4 + 2] += a1 * a4.z;
                acc1[kq * 4 + 3] += a1 * a4.w;
            }
        }
    }

    // ---- epilogue: subtract asum*c, atomic accumulate into out ----
    float* outb = out + (size_t)b * KK * DD;
#pragma unroll
    for (int k = 0; k < KK; ++k) {
        float as = asum_sm[k];
        float c0 = cw[k * DD + d0];
        float c1 = cw[k * DD + d1];
        atomicAdd(&outb[k * DD + d0], acc0[k] - as * c0);
        atomicAdd(&outb[k * DD + d1], acc1[k] - as * c1);
    }
}

extern "C" void kernel_launch(void* const* d_in, const int* in_sizes, int n_in,
                              void* d_out, int out_size, void* d_ws, size_t ws_size,
                              hipStream_t stream) {
    const float* x = (const float*)d_in[0];
    const float* cw = (const float*)d_in[1];
    const float* scale = (const float*)d_in[2];
    float* out = (float*)d_out;

    // zero output (harness poisons it; atomics need zeros)
    hipMemsetAsync(d_out, 0, (size_t)out_size * sizeof(float), stream);

    dim3 grid(BB * 16);   // 16 tiles of 256 n per batch
    dim3 block(BLK);
    encoding_fused<<<grid, block, 0, stream>>>(x, cw, scale, out);
}

// Round 2
// 67.130 us; speedup vs baseline: 3.2050x; 3.2050x over previous
//
#include <hip/hip_runtime.h>
#include <hip/hip_fp16.h>

#define BB 16
#define DD 512
#define NN 4096
#define KK 32
#define TN 128        // n-tile per block
#define NTILES 32     // tiles per batch
#define NBLK (BB*NTILES)   // 512 blocks
#define ROWL 136      // xb_sm row length (bf16 elems), 272 B, 16B-aligned
#define ROWA 136      // a_t row length

typedef unsigned short u16;
typedef __attribute__((ext_vector_type(8))) short short8v;
typedef __attribute__((ext_vector_type(4))) float f32x4;

// swizzled LDS element index for x tile: 8-elem (16 B) chunks XORed by d-bits
// keeps n-contiguity within chunks (b128 reads OK) and spreads the
// d-strided scalar reads across banks.
__device__ __forceinline__ int xidx(int d, int n) {
    return d * ROWL + (n & 7) + ((((n >> 3) ^ ((d >> 3) & 15))) << 3);
}

__device__ __forceinline__ u16 f2bf(float f) {
    union { float f; unsigned u; } v; v.f = f;
    unsigned r = v.u + 0x7fff + ((v.u >> 16) & 1);   // RNE
    return (u16)(r >> 16);
}

// ---------------- K0: prep codewords (bf16 copy, c2, s2) ----------------
__global__ void k0_prep(const float* __restrict__ cw, const float* __restrict__ scale,
                        u16* __restrict__ c_bf, float* __restrict__ c2,
                        float* __restrict__ s2) {
    int t = threadIdx.x;
    for (int i = t; i < KK * DD; i += 512) c_bf[i] = f2bf(cw[i]);
    if (t < KK) {
        float s = 0.f;
        for (int d = 0; d < DD; ++d) { float v = cw[t * DD + d]; s += v * v; }
        c2[t] = s;
        float sc = scale[t];
        s2[t] = sc * sc;
    }
}

// ---------------- K1: fused main kernel ----------------
template <typename PART>
__global__ __launch_bounds__(512, 1)
void k1_fused(const float* __restrict__ x, const u16* __restrict__ c_bf,
              const float* __restrict__ c2g, const float* __restrict__ s2g,
              float* __restrict__ ws_asum, PART* __restrict__ ws_e) {
    extern __shared__ char smem[];
    u16*   xb      = (u16*)smem;                       // [512][136] bf16: 139264 B
    u16*   a_t     = xb + DD * ROWL;                   // [32][136] bf16: 8704 B
    float* x2_part = (float*)(a_t + KK * ROWA);        // [16][128]: 8192 B
    float* x2      = x2_part + 16 * TN;                // [128]
    float* asum_p  = x2 + TN;                          // [8][32]

    const int t = threadIdx.x;
    const int l = t & 63, w = t >> 6;        // lane, wave (8 waves)
    const int g = l >> 4, li = l & 15;       // 16-lane group, group-lane
    const int blk = blockIdx.x;
    const int b = blk >> 5, tile = blk & 31;
    const int n0 = tile * TN;
    const float* xg = x + ((size_t)b * DD) * NN + n0;

    // ---- stage x tile -> LDS bf16 (swizzled); fp32 x2 partials ----
    {
        const int c = t & 31, rg = t >> 5;   // 32 lanes per row, 16 row-groups
        float p0 = 0, p1 = 0, p2 = 0, p3 = 0;
        for (int it = 0; it < 32; ++it) {
            int d = it * 16 + rg;
            float4 v = *(const float4*)(xg + (size_t)d * NN + 4 * c);
            uint2 pk;
            pk.x = (unsigned)f2bf(v.x) | ((unsigned)f2bf(v.y) << 16);
            pk.y = (unsigned)f2bf(v.z) | ((unsigned)f2bf(v.w) << 16);
            *(uint2*)(xb + xidx(d, 4 * c)) = pk;
            p0 += v.x * v.x; p1 += v.y * v.y; p2 += v.z * v.z; p3 += v.w * v.w;
        }
        x2_part[rg * TN + 4 * c + 0] = p0;
        x2_part[rg * TN + 4 * c + 1] = p1;
        x2_part[rg * TN + 4 * c + 2] = p2;
        x2_part[rg * TN + 4 * c + 3] = p3;
    }
    __syncthreads();

    // x2 reduce (threads 0..127), concurrent with phase A below
    if (t < TN) {
        float s = 0.f;
        #pragma unroll
        for (int gg = 0; gg < 16; ++gg) s += x2_part[gg * TN + t];
        x2[t] = s;
    }

    // ---- phase A: pre-logits = c . x   out[k=32][n: 16 per wave] ----
    f32x4 accA0 = {0.f, 0.f, 0.f, 0.f}, accA1 = {0.f, 0.f, 0.f, 0.f};
    {
        const int nloc = w * 16 + li;
        for (int ch = 0; ch < 16; ++ch) {
            const int dbase = ch * 32 + g * 8;
            const u16* p = xb + xidx(dbase, nloc);
            short8v bf;
            #pragma unroll
            for (int j = 0; j < 8; ++j) bf[j] = (short)p[j * ROWL];
            short8v a0 = *(const short8v*)(c_bf + (0 * 16 + li) * DD + dbase);
            short8v a1 = *(const short8v*)(c_bf + (1 * 16 + li) * DD + dbase);
            accA0 = __builtin_amdgcn_mfma_f32_16x16x32_bf16(a0, bf, accA0, 0, 0, 0);
            accA1 = __builtin_amdgcn_mfma_f32_16x16x32_bf16(a1, bf, accA1, 0, 0, 0);
        }
    }
    __syncthreads();

    // ---- softmax over k for column n = w*16+li; write a_t + asum partials ----
    {
        const int nloc = w * 16 + li;
        const float x2v = x2[nloc];
        float sl[8];
        float mx = -3.4e38f;
        #pragma unroll
        for (int r = 0; r < 4; ++r) {
            int k0 = 4 * g + r, k1 = 16 + 4 * g + r;
            float v0 = s2g[k0] * (x2v - 2.f * accA0[r] + c2g[k0]);
            float v1 = s2g[k1] * (x2v - 2.f * accA1[r] + c2g[k1]);
            sl[r] = v0; sl[4 + r] = v1;
            mx = fmaxf(mx, fmaxf(v0, v1));
        }
        mx = fmaxf(mx, __shfl_xor(mx, 16));
        mx = fmaxf(mx, __shfl_xor(mx, 32));
        float sum = 0.f;
        #pragma unroll
        for (int i = 0; i < 8; ++i) { sl[i] = __expf(sl[i] - mx); sum += sl[i]; }
        sum += __shfl_xor(sum, 16);
        sum += __shfl_xor(sum, 32);
        const float inv = 1.f / sum;
        #pragma unroll
        for (int i = 0; i < 8; ++i) {
            float a = sl[i] * inv;
            int k = (i < 4) ? (4 * g + i) : (16 + 4 * g + (i - 4));
            a_t[k * ROWA + nloc] = f2bf(a);
            float s = a;
            s += __shfl_xor(s, 1); s += __shfl_xor(s, 2);
            s += __shfl_xor(s, 4); s += __shfl_xor(s, 8);
            if (li == 0) asum_p[w * KK + k] = s;   // sum over this wave's 16 n
        }
    }
    __syncthreads();

    // asum partial for this block -> ws
    if (t < KK) {
        float s = 0.f;
        #pragma unroll
        for (int ww = 0; ww < 8; ++ww) s += asum_p[ww * KK + t];
        ws_asum[(size_t)blk * KK + t] = s;
    }

    // ---- phase B: e_partial[k=32][d: 64 per wave] = a . x^T ----
    f32x4 accB[2][4];
    #pragma unroll
    for (int kt = 0; kt < 2; ++kt)
        #pragma unroll
        for (int dt = 0; dt < 4; ++dt) accB[kt][dt] = (f32x4){0.f, 0.f, 0.f, 0.f};

    #pragma unroll
    for (int ch = 0; ch < 4; ++ch) {
        const int nb = ch * 32 + g * 8;
        short8v af0 = *(const short8v*)(a_t + (0 * 16 + li) * ROWA + nb);
        short8v af1 = *(const short8v*)(a_t + (1 * 16 + li) * ROWA + nb);
        #pragma unroll
        for (int dt = 0; dt < 4; ++dt) {
            const int d = w * 64 + dt * 16 + li;
            short8v xf = *(const short8v*)(xb + xidx(d, nb));
            accB[0][dt] = __builtin_amdgcn_mfma_f32_16x16x32_bf16(af0, xf, accB[0][dt], 0, 0, 0);
            accB[1][dt] = __builtin_amdgcn_mfma_f32_16x16x32_bf16(af1, xf, accB[1][dt], 0, 0, 0);
        }
    }

    // ---- write e partials ----
    const size_t ebase = (size_t)blk * KK * DD;
    #pragma unroll
    for (int kt = 0; kt < 2; ++kt)
        #pragma unroll
        for (int dt = 0; dt < 4; ++dt)
            #pragma unroll
            for (int r = 0; r < 4; ++r) {
                int k = kt * 16 + 4 * g + r;
                int d = w * 64 + dt * 16 + li;
                ws_e[ebase + (size_t)k * DD + d] = (PART)(accB[kt][dt][r]);
            }
}

// ---------------- K2: reduce partials, subtract asum*c ----------------
template <typename PART>
__global__ void k2_reduce(const PART* __restrict__ ws_e, const float* __restrict__ ws_asum,
                          const float* __restrict__ cw, float* __restrict__ out) {
    int tid = blockIdx.x * blockDim.x + threadIdx.x;   // 262144 = 16*32*512
    int d = tid & (DD - 1);
    int k = (tid >> 9) & (KK - 1);
    int b = tid >> 14;
    float s = 0.f, as = 0.f;
    for (int tl = 0; tl < NTILES; ++tl) {
        int blk = b * NTILES + tl;
        s += (float)ws_e[((size_t)blk * KK + k) * DD + d];
        as += ws_asum[(size_t)blk * KK + k];
    }
    out[tid] = s - as * cw[k * DD + d];
}

extern "C" void kernel_launch(void* const* d_in, const int* in_sizes, int n_in,
                              void* d_out, int out_size, void* d_ws, size_t ws_size,
                              hipStream_t stream) {
    const float* x = (const float*)d_in[0];
    const float* cw = (const float*)d_in[1];
    const float* scale = (const float*)d_in[2];
    float* out = (float*)d_out;

    char* ws = (char*)d_ws;
    u16*   c_bf    = (u16*)ws;                  // 32768 B
    float* c2      = (float*)(ws + 32768);      // 128 B
    float* s2      = (float*)(ws + 32896);      // 128 B
    float* ws_asum = (float*)(ws + 33024);      // 512*32*4 = 65536 B
    char*  e_ptr   = ws + 98560;

    const size_t need_f = 98560 + (size_t)NBLK * KK * DD * sizeof(float);
    const size_t lds = (size_t)(DD * ROWL + KK * ROWA) * 2 + (16 * TN + TN + 8 * KK) * 4;

    k0_prep<<<1, 512, 0, stream>>>(cw, scale, c_bf, c2, s2);
    if (ws_size >= need_f) {
        k1_fused<float><<<NBLK, 512, lds, stream>>>(x, c_bf, c2, s2, ws_asum, (float*)e_ptr);
        k2_reduce<float><<<(BB * KK * DD) / 256, 256, 0, stream>>>((float*)e_ptr, ws_asum, cw, out);
    } else {
        k1_fused<__half><<<NBLK, 512, lds, stream>>>(x, c_bf, c2, s2, ws_asum, (__half*)e_ptr);
        k2_reduce<__half><<<(BB * KK * DD) / 256, 256, 0, stream>>>((__half*)e_ptr, ws_asum, cw, out);
    }
}

// Round 3
// 57.314 us; speedup vs baseline: 3.7539x; 1.1713x over previous
//
#include <hip/hip_runtime.h>
#include <hip/hip_fp16.h>

#define BB 16
#define DD 512
#define NN 4096
#define KK 32
#define TN 128        // n-tile per block
#define NTILES 32     // tiles per batch
#define NBLK (BB*NTILES)   // 512 blocks
#define ROWL 136      // xb_sm row length (bf16 elems), 272 B, 16B-aligned
#define ROWA 136      // a_t row length

typedef unsigned short u16;
typedef __attribute__((ext_vector_type(8))) short short8v;
typedef __attribute__((ext_vector_type(4))) float f32x4;

// swizzled LDS element index for x tile: 8-elem (16 B) chunks XORed by d-bits
__device__ __forceinline__ int xidx(int d, int n) {
    return d * ROWL + (n & 7) + ((((n >> 3) ^ ((d >> 3) & 15))) << 3);
}

__device__ __forceinline__ unsigned f2bf(float f) {
    union { float f; unsigned u; } v; v.f = f;
    unsigned r = v.u + 0x7fff + ((v.u >> 16) & 1);   // RNE
    return r >> 16;
}

// ---------------- K0: prep codewords (bf16 copy, c2, s2); 1 wave per k ----
__global__ void k0_prep(const float* __restrict__ cw, const float* __restrict__ scale,
                        u16* __restrict__ c_bf, float* __restrict__ c2,
                        float* __restrict__ s2) {
    const int k = blockIdx.x;       // 32 blocks
    const int l = threadIdx.x;      // 64 threads
    const float* row = cw + k * DD;
    float s = 0.f;
#pragma unroll
    for (int j = 0; j < 8; ++j) {
        float v = row[j * 64 + l];
        s += v * v;
        c_bf[k * DD + j * 64 + l] = (u16)f2bf(v);
    }
#pragma unroll
    for (int off = 32; off; off >>= 1) s += __shfl_xor(s, off);
    if (l == 0) { c2[k] = s; float sc = scale[k]; s2[k] = sc * sc; }
}

// ---------------- K1: fused main kernel ----------------
template <typename PART>
__global__ __launch_bounds__(512, 1)
void k1_fused(const float* __restrict__ x, const u16* __restrict__ c_bf,
              const float* __restrict__ c2g, const float* __restrict__ s2g,
              float* __restrict__ ws_asum, PART* __restrict__ ws_e) {
    extern __shared__ char smem[];
    u16*   xb      = (u16*)smem;                       // [512][136] bf16
    u16*   a_t     = xb + DD * ROWL;                   // [32][136] bf16
    float* x2_part = (float*)(a_t + KK * ROWA);        // [16][128]
    float* x2      = x2_part + 16 * TN;                // [128]
    float* asum_p  = x2 + TN;                          // [8][32]

    const int t = threadIdx.x;
    const int l = t & 63, w = t >> 6;        // lane, wave (8 waves)
    const int g = l >> 4, li = l & 15;       // 16-lane group, group-lane
    const int blk = blockIdx.x;
    const int b = blk >> 5, tile = blk & 31;
    const int n0 = tile * TN;
    const float* xg = x + ((size_t)b * DD) * NN + n0;

    // ---- stage x tile -> LDS bf16 (swizzled); deep-pipelined loads ----
    {
        const int c = t & 31, rg = t >> 5;   // float4-col, row-group (16 groups)
        const float* bp = xg + (size_t)rg * NN + 4 * c;
        float4 v[32];
#pragma unroll
        for (int j = 0; j < 16; ++j) v[j] = *(const float4*)(bp + (size_t)(j * 16) * NN);
#pragma unroll
        for (int j = 16; j < 32; ++j) v[j] = *(const float4*)(bp + (size_t)(j * 16) * NN);
        float p0 = 0, p1 = 0, p2 = 0, p3 = 0;
#pragma unroll
        for (int j = 0; j < 32; ++j) {
            const int d = j * 16 + rg;
            uint2 pk;
            pk.x = f2bf(v[j].x) | (f2bf(v[j].y) << 16);
            pk.y = f2bf(v[j].z) | (f2bf(v[j].w) << 16);
            *(uint2*)(xb + xidx(d, 4 * c)) = pk;
            p0 += v[j].x * v[j].x; p1 += v[j].y * v[j].y;
            p2 += v[j].z * v[j].z; p3 += v[j].w * v[j].w;
        }
        x2_part[rg * TN + 4 * c + 0] = p0;
        x2_part[rg * TN + 4 * c + 1] = p1;
        x2_part[rg * TN + 4 * c + 2] = p2;
        x2_part[rg * TN + 4 * c + 3] = p3;
    }
    __syncthreads();

    // x2 reduce (threads 0..127), concurrent with phase A
    if (t < TN) {
        float s = 0.f;
        #pragma unroll
        for (int gg = 0; gg < 16; ++gg) s += x2_part[gg * TN + t];
        x2[t] = s;
    }

    // ---- phase A: pre-logits = c . x   out[k=32][n: 16 per wave] ----
    f32x4 accA0 = {0.f, 0.f, 0.f, 0.f}, accA1 = {0.f, 0.f, 0.f, 0.f};
    {
        const int nloc = w * 16 + li;
        for (int ch = 0; ch < 16; ++ch) {
            const int dbase = ch * 32 + g * 8;
            const u16* p = xb + xidx(dbase, nloc);
            short8v bf;
            #pragma unroll
            for (int j = 0; j < 8; ++j) bf[j] = (short)p[j * ROWL];
            short8v a0 = *(const short8v*)(c_bf + (0 * 16 + li) * DD + dbase);
            short8v a1 = *(const short8v*)(c_bf + (1 * 16 + li) * DD + dbase);
            accA0 = __builtin_amdgcn_mfma_f32_16x16x32_bf16(a0, bf, accA0, 0, 0, 0);
            accA1 = __builtin_amdgcn_mfma_f32_16x16x32_bf16(a1, bf, accA1, 0, 0, 0);
        }
    }
    __syncthreads();

    // ---- softmax over k for column n = w*16+li ----
    {
        const int nloc = w * 16 + li;
        const float x2v = x2[nloc];
        float sl[8];
        float mx = -3.4e38f;
        #pragma unroll
        for (int r = 0; r < 4; ++r) {
            int k0 = 4 * g + r, k1 = 16 + 4 * g + r;
            float v0 = s2g[k0] * (x2v - 2.f * accA0[r] + c2g[k0]);
            float v1 = s2g[k1] * (x2v - 2.f * accA1[r] + c2g[k1]);
            sl[r] = v0; sl[4 + r] = v1;
            mx = fmaxf(mx, fmaxf(v0, v1));
        }
        mx = fmaxf(mx, __shfl_xor(mx, 16));
        mx = fmaxf(mx, __shfl_xor(mx, 32));
        float sum = 0.f;
        #pragma unroll
        for (int i = 0; i < 8; ++i) { sl[i] = __expf(sl[i] - mx); sum += sl[i]; }
        sum += __shfl_xor(sum, 16);
        sum += __shfl_xor(sum, 32);
        const float inv = 1.f / sum;
        #pragma unroll
        for (int i = 0; i < 8; ++i) {
            float a = sl[i] * inv;
            int k = (i < 4) ? (4 * g + i) : (16 + 4 * g + (i - 4));
            a_t[k * ROWA + nloc] = (u16)f2bf(a);
            float s = a;
            s += __shfl_xor(s, 1); s += __shfl_xor(s, 2);
            s += __shfl_xor(s, 4); s += __shfl_xor(s, 8);
            if (li == 0) asum_p[w * KK + k] = s;
        }
    }
    __syncthreads();

    if (t < KK) {
        float s = 0.f;
        #pragma unroll
        for (int ww = 0; ww < 8; ++ww) s += asum_p[ww * KK + t];
        ws_asum[(size_t)blk * KK + t] = s;
    }

    // ---- phase B: e_partial[k=32][d: 64 per wave] = a . x^T ----
    f32x4 accB[2][4];
    #pragma unroll
    for (int kt = 0; kt < 2; ++kt)
        #pragma unroll
        for (int dt = 0; dt < 4; ++dt) accB[kt][dt] = (f32x4){0.f, 0.f, 0.f, 0.f};

    #pragma unroll
    for (int ch = 0; ch < 4; ++ch) {
        const int nb = ch * 32 + g * 8;
        short8v af0 = *(const short8v*)(a_t + (0 * 16 + li) * ROWA + nb);
        short8v af1 = *(const short8v*)(a_t + (1 * 16 + li) * ROWA + nb);
        #pragma unroll
        for (int dt = 0; dt < 4; ++dt) {
            const int d = w * 64 + dt * 16 + li;
            short8v xf = *(const short8v*)(xb + xidx(d, nb));
            accB[0][dt] = __builtin_amdgcn_mfma_f32_16x16x32_bf16(af0, xf, accB[0][dt], 0, 0, 0);
            accB[1][dt] = __builtin_amdgcn_mfma_f32_16x16x32_bf16(af1, xf, accB[1][dt], 0, 0, 0);
        }
    }

    // ---- write e partials ----
    const size_t ebase = (size_t)blk * KK * DD;
    #pragma unroll
    for (int kt = 0; kt < 2; ++kt)
        #pragma unroll
        for (int dt = 0; dt < 4; ++dt)
            #pragma unroll
            for (int r = 0; r < 4; ++r) {
                int k = kt * 16 + 4 * g + r;
                int d = w * 64 + dt * 16 + li;
                ws_e[ebase + (size_t)k * DD + d] = (PART)(accB[kt][dt][r]);
            }
}

// ---------------- K2: reduce partials (half2), subtract asum*c ----------
__global__ void k2_reduce_h(const __half2* __restrict__ ws_e, const float* __restrict__ ws_asum,
                            const float* __restrict__ cw, float* __restrict__ out) {
    int tid = blockIdx.x * blockDim.x + threadIdx.x;   // 131072
    int d2 = tid & 255;
    int k = (tid >> 8) & (KK - 1);
    int b = tid >> 13;
    const __half2* pe = ws_e + ((size_t)(b * NTILES) * KK + k) * 256 + d2;
    const float* pa = ws_asum + b * NTILES * KK + k;
    float s0 = 0.f, s1 = 0.f, as = 0.f;
    for (int tl = 0; tl < NTILES; ++tl) {
        float2 f = __half22float2(pe[(size_t)tl * KK * 256]);
        s0 += f.x; s1 += f.y;
        as += pa[tl * KK];
    }
    int d = d2 * 2;
    float c0 = cw[k * DD + d], c1 = cw[k * DD + d + 1];
    float2 o; o.x = s0 - as * c0; o.y = s1 - as * c1;
    *(float2*)(out + ((size_t)(b * KK + k) * DD + d)) = o;
}

__global__ void k2_reduce_f(const float* __restrict__ ws_e, const float* __restrict__ ws_asum,
                            const float* __restrict__ cw, float* __restrict__ out) {
    int tid = blockIdx.x * blockDim.x + threadIdx.x;   // 262144
    int d = tid & (DD - 1);
    int k = (tid >> 9) & (KK - 1);
    int b = tid >> 14;
    float s = 0.f, as = 0.f;
    for (int tl = 0; tl < NTILES; ++tl) {
        int blk = b * NTILES + tl;
        s += ws_e[((size_t)blk * KK + k) * DD + d];
        as += ws_asum[(size_t)blk * KK + k];
    }
    out[tid] = s - as * cw[k * DD + d];
}

extern "C" void kernel_launch(void* const* d_in, const int* in_sizes, int n_in,
                              void* d_out, int out_size, void* d_ws, size_t ws_size,
                              hipStream_t stream) {
    const float* x = (const float*)d_in[0];
    const float* cw = (const float*)d_in[1];
    const float* scale = (const float*)d_in[2];
    float* out = (float*)d_out;

    char* ws = (char*)d_ws;
    u16*   c_bf    = (u16*)ws;                  // 32768 B
    float* c2      = (float*)(ws + 32768);
    float* s2      = (float*)(ws + 32896);
    float* ws_asum = (float*)(ws + 33024);      // 65536 B
    char*  e_ptr   = ws + 98560;

    const size_t lds = (size_t)(DD * ROWL + KK * ROWA) * 2 + (16 * TN + TN + 8 * KK) * 4;
    const size_t need_h = 98560 + (size_t)NBLK * KK * DD * sizeof(__half);

    k0_prep<<<KK, 64, 0, stream>>>(cw, scale, c_bf, c2, s2);
    if (ws_size >= need_h) {
        k1_fused<__half><<<NBLK, 512, lds, stream>>>(x, c_bf, c2, s2, ws_asum, (__half*)e_ptr);
        k2_reduce_h<<<(BB * KK * 256) / 256, 256, 0, stream>>>((const __half2*)e_ptr, ws_asum, cw, out);
    } else {
        k1_fused<float><<<NBLK, 512, lds, stream>>>(x, c_bf, c2, s2, ws_asum, (float*)e_ptr);
        k2_reduce_f<<<(BB * KK * DD) / 256, 256, 0, stream>>>((const float*)e_ptr, ws_asum, cw, out);
    }
}